// Round 16
// baseline (91.339 us; speedup 1.0000x reference)
//
#include <hip/hip_runtime.h>
#include <cstdint>

// ---- problem constants ----
#define B_ROWS 8192
#define XSTR   406      // x row stride (ints)
#define GAMMA_C 12.0f
#define SCALE_ANG 30.994217f   // PI / sqrt(6/584)

#define KH     1024            // padded t-range (1000 -> 1024)

// prepG grid: tab | wcat | G-build
#define NT_BLK 128             // tab frags: 4/block (512)
#define NW_BLK 64              // wcat frags: 4/block (256)
#define NG_BLK 2048            // G build: 4 batch-rows/block
#define NPREP  (NT_BLK + NW_BLK + NG_BLK)

// merged grid: fused blocks first, then sabs blocks
#define NF_BLK 256             // fused: 32 rows/block (2 pairs x 16)
#define NS_BLK 4096            // sabs: 2 rows/block
#define NMRG   (NF_BLK + NS_BLK)

// workspace layout (full path)
#define TF_BYTES    (KH*256*2)          // 524288   : tab, B-frag order
#define WCAT_BYTES  (512*256*2)         // 262144   : sign-folded w_e, B-frag order
#define G_BYTES     (8192*KH*2)         // 16777216 : signed histogram bf16
#define WS_FULL     ((size_t)(TF_BYTES + WCAT_BYTES + G_BYTES))
// fallback path
#define OLDTAB_BYTES (1000*256*2)
#define WS_OLD       ((size_t)(OLDTAB_BYTES + WCAT_BYTES))

typedef __attribute__((ext_vector_type(8))) short short8v;
typedef __attribute__((ext_vector_type(4))) float float4v;

__device__ __forceinline__ float bfLo(uint32_t u) { return __uint_as_float(u << 16); }
__device__ __forceinline__ float bfHi(uint32_t u) { return __uint_as_float(u & 0xffff0000u); }
__device__ __forceinline__ float bf1(unsigned short u) { return __uint_as_float((uint32_t)u << 16); }

__device__ __forceinline__ uint32_t f2bf_u(float x) {
  uint32_t u = __float_as_uint(x);
  u += 0x7fffu + ((u >> 16) & 1u);   // RNE
  return u >> 16;
}
__device__ __forceinline__ unsigned short f2bf(float x) { return (unsigned short)f2bf_u(x); }

__device__ __forceinline__ short8v cvt8(float4 a, float4 b) {
  short8v r;
  r[0] = (short)f2bf(a.x); r[1] = (short)f2bf(a.y);
  r[2] = (short)f2bf(a.z); r[3] = (short)f2bf(a.w);
  r[4] = (short)f2bf(b.x); r[5] = (short)f2bf(b.y);
  r[6] = (short)f2bf(b.z); r[7] = (short)f2bf(b.w);
  return r;
}

// ---------------------------------------------------------------------------
// Kernel 1: tab + wcat frags + G histogram build (all high-occupancy).
// B-frag swizzle: frag fb, lane l, elem j <-> k=(fb>>4)*32+(l>>4)*8+j, c=(fb&15)*16+(l&15)
__global__ __launch_bounds__(256) void kge_prepG(
    const int* __restrict__ x, const float* __restrict__ w_rp,
    const float* __restrict__ w_e,
    unsigned short* __restrict__ tf, unsigned short* __restrict__ wcat,
    unsigned short* __restrict__ G) {
  __shared__ float Hl[4][KH];   // 16 KB (G branch only)
  const int bid = blockIdx.x;
  const int tid = threadIdx.x;
  const int sub = tid >> 6, l = tid & 63;

  if (bid < NT_BLK) {
    // tab frags: value(k,c) = k<1000 ? (c<128 ? cos : sin)(k*f_{c&127}) : 0
    const int fragid = bid * 4 + sub;   // kt*16+nt
    const int kt = fragid >> 4, nt = fragid & 15;
    const int c = nt * 16 + (l & 15);
    const float f = exp2f(-(float)(c & 127) * (13.287712379549449f / 128.f));
    __align__(16) unsigned short v[8];
    #pragma unroll
    for (int jj = 0; jj < 8; ++jj) {
      int k = kt * 32 + ((l >> 4) << 3) + jj;
      float val = 0.f;
      if (k < 1000) {
        float s, cv;
        sincosf((float)k * f, &s, &cv);
        val = (c < 128) ? cv : s;
      }
      v[jj] = f2bf(val);
    }
    ((uint4*)tf)[fragid * 64 + l] = *(const uint4*)v;
  } else if (bid < NT_BLK + NW_BLK) {
    // Wcat frags: Wcat[k][c] = c<128 ? s(k)*w_e[k][c] : -s(k)*w_e[k^256][c-128]
    const int fragid = (bid - NT_BLK) * 4 + sub;
    const int kk = fragid >> 4, nt = fragid & 15;
    const int c = nt * 16 + (l & 15);
    __align__(16) unsigned short v[8];
    #pragma unroll
    for (int jj = 0; jj < 8; ++jj) {
      int k = kk * 32 + ((l >> 4) << 3) + jj;
      float s = (k < 256) ? 1.f : -1.f;
      float val = (c < 128) ? s * w_e[k * 128 + c]
                            : -s * w_e[(k ^ 256) * 128 + (c - 128)];
      v[jj] = f2bf(val);
    }
    ((uint4*)wcat)[fragid * 64 + l] = *(const uint4*)v;
  } else {
    // G[row][t] = sum_n w[n]*(delta(cS[n]=t) - delta(cO[n]=t)); 4 rows/block
    const int row = (bid - NT_BLK - NW_BLK) * 4 + sub;
    float4 z = {0, 0, 0, 0};
    for (int i = l; i < KH / 4; i += 64) ((float4*)Hl[sub])[i] = z;
    const int rid = x[(size_t)row * XSTR + 1];
    const int* cp = x + (size_t)row * XSTR + 6;
    const float* wp = w_rp + (size_t)rid * 200;
    for (int n = l; n < 200; n += 64) {
      float wv = wp[n];
      atomicAdd(&Hl[sub][cp[n]], wv);
      atomicAdd(&Hl[sub][cp[200 + n]], -wv);
    }
    unsigned short* dst = G + (size_t)row * KH;
    for (int i = l; i < KH / 2; i += 64) {
      float a = Hl[sub][2 * i], b = Hl[sub][2 * i + 1];
      ((uint32_t*)dst)[i] = f2bf_u(a) | (f2bf_u(b) << 16);
    }
  }
}

// ---------------------------------------------------------------------------
// Kernel 2 (merged): fused diff-GEMM+sc_rel blocks co-scheduled with sc_abs
// gather blocks. Shared 32KB union keeps LDS ~33KB -> 4 blocks/CU (16 w/CU).
// Each row's score = two atomicAdds into memset-zero out:
//   fused block adds -srel; sabs block adds (GAMMA - sabs).
__global__ __launch_bounds__(256) void kge_merged2(
    const int* __restrict__ x, const float* __restrict__ e_emb,
    const float* __restrict__ r_emb,
    const float* __restrict__ d_frq, const float* __restrict__ d_phi, const float* __restrict__ d_amp,
    const float* __restrict__ m_frq, const float* __restrict__ m_phi, const float* __restrict__ m_amp,
    const unsigned short* __restrict__ G,
    const unsigned short* __restrict__ wcat, const unsigned short* __restrict__ tf,
    float* __restrict__ out) {
  __shared__ __align__(16) float shbuf[2 * 16 * 256];   // 32 KB union
  __shared__ float srl[32];
  __shared__ float redl[4];
  const int tid = threadIdx.x;
  const int w = tid >> 6, l = tid & 63;

  if (blockIdx.x < NF_BLK) {
    // ========== fused path: 32 rows/block = 2 pairs x 16 rows ==========
    const int m0 = blockIdx.x * 32;
    const int pair = w >> 1, kh = w & 1;
    const int mrow = m0 + pair * 16;

    const int rowA = mrow + (l & 15);
    const unsigned short* Gp = G + (size_t)rowA * KH + ((l >> 4) << 3);
    const short8v* wq = (const short8v*)wcat;
    const short8v* tq = (const short8v*)tf;

    float4v acc[16];
    #pragma unroll
    for (int i = 0; i < 16; ++i) acc[i] = (float4v){0, 0, 0, 0};

    if (kh == 0) {
      const int* xrA = x + (size_t)rowA * XSTR;
      const float* Esp = e_emb + (size_t)xrA[0] * 512 + ((l >> 4) << 3);
      const float* Eop = e_emb + (size_t)xrA[2] * 512 + ((l >> 4) << 3);
      // e_emb-diff K-steps 0..15 (wcat B)
      #pragma unroll 2
      for (int kt = 0; kt < 16; ++kt) {
        float4 s0 = *(const float4*)(Esp + kt * 32);
        float4 s1 = *(const float4*)(Esp + kt * 32 + 4);
        float4 o0 = *(const float4*)(Eop + kt * 32);
        float4 o1 = *(const float4*)(Eop + kt * 32 + 4);
        float4 d0 = {s0.x - o0.x, s0.y - o0.y, s0.z - o0.z, s0.w - o0.w};
        float4 d1 = {s1.x - o1.x, s1.y - o1.y, s1.z - o1.z, s1.w - o1.w};
        short8v a = cvt8(d0, d1);
        const short8v* bsrc = wq + (size_t)kt * 1024;
        #pragma unroll
        for (int nt = 0; nt < 16; ++nt)
          acc[nt] = __builtin_amdgcn_mfma_f32_16x16x32_bf16(a, bsrc[nt * 64 + l], acc[nt], 0, 0, 0);
      }
      // G steps 0..7
      #pragma unroll 2
      for (int g = 0; g < 8; ++g) {
        short8v a = *(const short8v*)(Gp + g * 32);
        const short8v* bsrc = tq + (size_t)g * 1024;
        #pragma unroll
        for (int nt = 0; nt < 16; ++nt)
          acc[nt] = __builtin_amdgcn_mfma_f32_16x16x32_bf16(a, bsrc[nt * 64 + l], acc[nt], 0, 0, 0);
      }
    } else {
      // G steps 8..31
      #pragma unroll 2
      for (int g = 8; g < 32; ++g) {
        short8v a = *(const short8v*)(Gp + g * 32);
        const short8v* bsrc = tq + (size_t)g * 1024;
        #pragma unroll
        for (int nt = 0; nt < 16; ++nt)
          acc[nt] = __builtin_amdgcn_mfma_f32_16x16x32_bf16(a, bsrc[nt * 64 + l], acc[nt], 0, 0, 0);
      }
      // hand off partials: cmb[pair][nt][q*64+l]
      #pragma unroll
      for (int nt = 0; nt < 16; ++nt)
        #pragma unroll
        for (int q = 0; q < 4; ++q)
          shbuf[(pair * 16 + nt) * 256 + q * 64 + l] = acc[nt][q];
    }
    __syncthreads();

    if (kh == 0) {
      // combine + sc_rel: C row=(l>>4)*4+q, col=nt*16+(l&15); re nt<8, im nt+8
      #pragma unroll
      for (int q = 0; q < 4; ++q) {
        float s = 0.f;
        #pragma unroll
        for (int nt = 0; nt < 8; ++nt) {
          const int idx = q * 64 + l;
          float dre = acc[nt][q]     + shbuf[(pair * 16 + nt) * 256 + idx];
          float dim = acc[nt + 8][q] + shbuf[(pair * 16 + nt + 8) * 256 + idx];
          s += sqrtf(dre * dre + dim * dim);
        }
        s += __shfl_xor(s, 1); s += __shfl_xor(s, 2);
        s += __shfl_xor(s, 4); s += __shfl_xor(s, 8);
        if ((l & 15) == 0) srl[pair * 16 + (l >> 4) * 4 + q] = s;
      }
    }
    __syncthreads();
    if (tid < 32) atomicAdd(&out[m0 + tid], -srl[tid]);
  } else {
    // ========== sc_abs path (2 rows/block, 128 thr/row) ==========
    float (*st2)[2][256] = (float(*)[2][256])shbuf;   // 4 KB inside union
    const int bid = blockIdx.x - NF_BLK;
    const int rsub = tid >> 7;               // row slot 0/1
    const int row = bid * 2 + rsub;
    const int j = tid & 127;
    const int* xr = x + (size_t)row * XSTR;
    const int eS = xr[0], rid = xr[1], eO = xr[2];
    const float dv = (float)xr[3], mv = (float)xr[4];
    const int j2 = 2 * j;
    #pragma unroll
    for (int ent = 0; ent < 2; ++ent) {
      const int e = ent ? eO : eS;
      float2 fd = *(const float2*)&d_frq[(size_t)e * 256 + j2];
      float2 pd = *(const float2*)&d_phi[(size_t)e * 256 + j2];
      float2 fm = *(const float2*)&m_frq[(size_t)e * 256 + j2];
      float2 pm = *(const float2*)&m_phi[(size_t)e * 256 + j2];
      const int ja = j2 & 127;
      float2 ad = *(const float2*)&d_amp[(size_t)e * 128 + ja];
      float2 am = *(const float2*)&m_amp[(size_t)e * 128 + ja];
      float a0 = fmaf(dv, fd.x, pd.x), a1 = fmaf(dv, fd.y, pd.y);
      float b0 = fmaf(mv, fm.x, pm.x), b1 = fmaf(mv, fm.y, pm.y);
      float t0, t1, u0, u1;
      if (j2 < 128) { t0 = __cosf(a0); t1 = __cosf(a1); u0 = __cosf(b0); u1 = __cosf(b1); }
      else          { t0 = __sinf(a0); t1 = __sinf(a1); u0 = __sinf(b0); u1 = __sinf(b1); }
      st2[rsub][ent][j2]     = fmaf(ad.x, t0, am.x * u0);
      st2[rsub][ent][j2 + 1] = fmaf(ad.y, t1, am.y * u1);
    }
    __syncthreads();
    const float* Es = e_emb + (size_t)eS * 512;
    const float* Eo = e_emb + (size_t)eO * 512;
    const float* Rr = r_emb + (size_t)rid * 384;
    float sabs = 0.f;
    #pragma unroll
    for (int t3 = 0; t3 < 3; ++t3) {
      const int u = t3 * 128 + j;
      float ang = Rr[u] * SCALE_ANG;
      float sr = __sinf(ang), cr = __cosf(ang);
      float res, ims, reo, imo;
      if (t3 < 2) {
        res = Es[u]; ims = Es[256 + u];
        reo = Eo[u]; imo = Eo[256 + u];
      } else {
        res = st2[rsub][0][j]; ims = st2[rsub][0][128 + j];
        reo = st2[rsub][1][j]; imo = st2[rsub][1][128 + j];
      }
      float rsc = res * cr - ims * sr - reo;
      float isc = res * sr + ims * cr - imo;
      sabs += sqrtf(rsc * rsc + isc * isc);
    }
    #pragma unroll
    for (int off = 32; off > 0; off >>= 1) sabs += __shfl_down(sabs, off);
    if (l == 0) redl[w] = sabs;
    __syncthreads();
    if (j == 0) atomicAdd(&out[row], GAMMA_C - (redl[2 * rsub] + redl[2 * rsub + 1]));
  }
}

// ===========================================================================
// Fallback path (workspace >= 774 KB but < WS_FULL): round-3 kernel.
#define NTH    512
#define RPB    8
#define ERB    (2*RPB)
#define APAD   520

__global__ void kge_table_old(unsigned short* __restrict__ tab) {
  int t = blockIdx.x;
  int j = threadIdx.x;
  double f = pow(10000.0, -(double)j / 128.0);
  double ang = (double)t * f;
  int q = j >> 1, lo = j & 1;
  tab[t * 256 + 4 * q + lo]     = f2bf((float)cos(ang));
  tab[t * 256 + 4 * q + 2 + lo] = f2bf((float)sin(ang));
}

__global__ void kge_wcat_old(const float* __restrict__ w_e, unsigned short* __restrict__ wcat) {
  int bid = blockIdx.x;
  int kk = bid >> 4, nt = bid & 15;
  int l = threadIdx.x;
  __align__(16) unsigned short v[8];
  int c = nt * 16 + (l & 15);
  #pragma unroll
  for (int j = 0; j < 8; ++j) {
    int k = kk * 32 + ((l >> 4) << 3) + j;
    float s = (k < 256) ? 1.f : -1.f;
    float val = (c < 128) ? s * w_e[k * 128 + c]
                          : -s * w_e[(k ^ 256) * 128 + (c - 128)];
    v[j] = f2bf(val);
  }
  ((uint4*)wcat)[bid * 64 + l] = *(const uint4*)v;
}

__global__ __launch_bounds__(NTH, 4) void kge_main3(
    const int* __restrict__ x,
    const float* __restrict__ e_emb, const float* __restrict__ r_emb,
    const float* __restrict__ d_frq, const float* __restrict__ d_phi, const float* __restrict__ d_amp,
    const float* __restrict__ m_frq, const float* __restrict__ m_phi, const float* __restrict__ m_amp,
    const float* __restrict__ w_rp,
    const unsigned short* __restrict__ tab, const unsigned short* __restrict__ wcat,
    float* __restrict__ out) {
  __shared__ __align__(16) unsigned short A[ERB][APAD];
  __shared__ __align__(16) unsigned short stb[ERB][256];
  __shared__ __align__(16) float p[ERB][256];
  __shared__ int meta[RPB][6];

  const int tid = threadIdx.x;
  const int base_row = blockIdx.x * RPB;
  const int w = tid >> 6, l = tid & 63;

  if (tid < RPB * 6) {
    int r = tid / 6, f = tid % 6;
    meta[r][f] = x[(size_t)(base_row + r) * XSTR + f];
  }
  __syncthreads();

  for (int i = tid; i < ERB * 128; i += NTH) {
    int er = i >> 7, k4 = i & 127;
    int e = (er & 1) ? meta[er >> 1][2] : meta[er >> 1][0];
    float4 v = ((const float4*)e_emb)[(size_t)e * 128 + k4];
    uint2 pk;
    pk.x = f2bf_u(v.x) | (f2bf_u(v.y) << 16);
    pk.y = f2bf_u(v.z) | (f2bf_u(v.w) << 16);
    *(uint2*)&A[er][k4 * 4] = pk;
  }
  for (int it = tid; it < ERB * 256; it += NTH) {
    int j = it & 255, er = it >> 8, r = er >> 1;
    int e = (er & 1) ? meta[r][2] : meta[r][0];
    float dv = (float)meta[r][3], mv = (float)meta[r][4];
    size_t b256 = (size_t)e * 256 + j, b128 = (size_t)e * 128 + (j & 127);
    float argd = fmaf(dv, d_frq[b256], d_phi[b256]);
    float argm = fmaf(mv, m_frq[b256], m_phi[b256]);
    float vd = (j < 128) ? d_amp[b128] * __cosf(argd) : d_amp[b128] * __sinf(argd);
    float vm = (j < 128) ? m_amp[b128] * __cosf(argm) : m_amp[b128] * __sinf(argm);
    stb[er][j] = f2bf(vd + vm);
  }

  float s0 = 0, s1 = 0, s2 = 0, s3 = 0, o0 = 0, o1 = 0, o2 = 0, o3 = 0;
  {
    const int wu  = __builtin_amdgcn_readfirstlane(w);
    const int rid = __builtin_amdgcn_readfirstlane(meta[wu][1]);
    const int*   cp = x + (size_t)(base_row + wu) * XSTR + 6;
    const float* wp = w_rp + (size_t)rid * 200;
    const uint2* tl = ((const uint2*)tab) + l;
    #pragma unroll 2
    for (int n = 0; n < 200; ++n) {
      float wv = wp[n];
      int cS = cp[n];
      int cO = cp[200 + n];
      uint2 qs = tl[(size_t)cS * 64];
      uint2 qo = tl[(size_t)cO * 64];
      s0 = fmaf(wv, bfLo(qs.x), s0); s1 = fmaf(wv, bfHi(qs.x), s1);
      s2 = fmaf(wv, bfLo(qs.y), s2); s3 = fmaf(wv, bfHi(qs.y), s3);
      o0 = fmaf(wv, bfLo(qo.x), o0); o1 = fmaf(wv, bfHi(qo.x), o1);
      o2 = fmaf(wv, bfLo(qo.y), o2); o3 = fmaf(wv, bfHi(qo.y), o3);
    }
  }
  __syncthreads();

  {
    float4v acc0 = {0, 0, 0, 0}, acc1 = {0, 0, 0, 0};
    const int nt0 = 2 * w, nt1 = 2 * w + 1;
    const short8v* bp = (const short8v*)wcat;
    const unsigned short* arow = &A[l & 15][(l >> 4) << 3];
    #pragma unroll 8
    for (int kk = 0; kk < 16; ++kk) {
      short8v a  = *(const short8v*)(arow + kk * 32);
      short8v b0 = bp[(kk * 16 + nt0) * 64 + l];
      short8v b1 = bp[(kk * 16 + nt1) * 64 + l];
      acc0 = __builtin_amdgcn_mfma_f32_16x16x32_bf16(a, b0, acc0, 0, 0, 0);
      acc1 = __builtin_amdgcn_mfma_f32_16x16x32_bf16(a, b1, acc1, 0, 0, 0);
    }
    int col = l & 15, rbase = (l >> 4) * 4;
    #pragma unroll
    for (int q = 0; q < 4; ++q) {
      p[rbase + q][nt0 * 16 + col] = acc0[q];
      p[rbase + q][nt1 * 16 + col] = acc1[q];
    }
  }
  __syncthreads();

  {
    int es = 2 * w, eo = 2 * w + 1;
    p[es][2 * l] += s0; p[es][2 * l + 1] += s1;
    p[es][128 + 2 * l] += s2; p[es][129 + 2 * l] += s3;
    p[eo][2 * l] += o0; p[eo][2 * l + 1] += o1;
    p[eo][128 + 2 * l] += o2; p[eo][129 + 2 * l] += o3;
  }
  __syncthreads();

  {
    int r = w;
    int rid = meta[r][1];
    float sabs = 0.f;
    #pragma unroll
    for (int u0 = 0; u0 < 384; u0 += 64) {
      int u = u0 + l;
      float ang = r_emb[(size_t)rid * 384 + u] * SCALE_ANG;
      float sr = __sinf(ang), cr = __cosf(ang);
      float res, ims, reo, imo;
      if (u < 256) {
        res = bf1(A[2 * r][u]);       ims = bf1(A[2 * r][256 + u]);
        reo = bf1(A[2 * r + 1][u]);   imo = bf1(A[2 * r + 1][256 + u]);
      } else {
        int uu = u - 256;
        res = bf1(stb[2 * r][uu]);     ims = bf1(stb[2 * r][128 + uu]);
        reo = bf1(stb[2 * r + 1][uu]); imo = bf1(stb[2 * r + 1][128 + uu]);
      }
      float rsc = res * cr - ims * sr - reo;
      float isc = res * sr + ims * cr - imo;
      sabs += sqrtf(rsc * rsc + isc * isc);
    }
    float srel = 0.f;
    #pragma unroll
    for (int u0 = 0; u0 < 128; u0 += 64) {
      int u = u0 + l;
      float dre = p[2 * r][u] - p[2 * r + 1][u];
      float dim = p[2 * r][128 + u] - p[2 * r + 1][128 + u];
      srel += sqrtf(dre * dre + dim * dim);
    }
    float tot = sabs + srel;
    #pragma unroll
    for (int off = 32; off > 0; off >>= 1) tot += __shfl_down(tot, off);
    if (l == 0) out[base_row + r] = GAMMA_C - tot;
  }
}

// ===========================================================================
extern "C" void kernel_launch(void* const* d_in, const int* in_sizes, int n_in,
                              void* d_out, int out_size, void* d_ws, size_t ws_size,
                              hipStream_t stream) {
  (void)in_sizes; (void)n_in; (void)out_size;
  const int*   x     = (const int*)d_in[0];
  const float* e_emb = (const float*)d_in[1];
  const float* r_emb = (const float*)d_in[2];
  const float* d_frq = (const float*)d_in[3];
  const float* d_phi = (const float*)d_in[4];
  const float* d_amp = (const float*)d_in[5];
  const float* m_frq = (const float*)d_in[6];
  const float* m_phi = (const float*)d_in[7];
  const float* m_amp = (const float*)d_in[8];
  const float* w_e   = (const float*)d_in[9];
  const float* w_rp  = (const float*)d_in[10];
  float* out = (float*)d_out;

  if (ws_size >= WS_FULL) {
    char* base = (char*)d_ws;
    unsigned short* tf   = (unsigned short*)base;
    unsigned short* wcat = (unsigned short*)(base + TF_BYTES);
    unsigned short* G    = (unsigned short*)(base + TF_BYTES + WCAT_BYTES);
    hipMemsetAsync(out, 0, (size_t)B_ROWS * sizeof(float), stream);
    kge_prepG<<<dim3(NPREP), dim3(256), 0, stream>>>(x, w_rp, w_e, tf, wcat, G);
    kge_merged2<<<dim3(NMRG), dim3(256), 0, stream>>>(
        x, e_emb, r_emb, d_frq, d_phi, d_amp, m_frq, m_phi, m_amp,
        G, wcat, tf, out);
  } else if (ws_size >= WS_OLD) {
    unsigned short* tab  = (unsigned short*)d_ws;
    unsigned short* wcat = (unsigned short*)((char*)d_ws + OLDTAB_BYTES);
    kge_table_old<<<dim3(1000), dim3(128), 0, stream>>>(tab);
    kge_wcat_old<<<dim3(256), dim3(64), 0, stream>>>(w_e, wcat);
    kge_main3<<<dim3(B_ROWS / RPB), dim3(NTH), 0, stream>>>(
        x, e_emb, r_emb, d_frq, d_phi, d_amp, m_frq, m_phi, m_amp, w_rp,
        tab, wcat, out);
  }
}

// Round 17
// 58.910 us; speedup vs baseline: 1.5505x; 1.5505x over previous
//
#include <hip/hip_runtime.h>
#include <cstdint>

// ---- problem constants ----
#define B_ROWS 8192
#define XSTR   406      // x row stride (ints)
#define GAMMA_C 12.0f
#define SCALE_ANG 30.994217f   // PI / sqrt(6/584)

#define KH     1024            // padded t-range (1000 -> 1024)
#define HPAD   1028            // hist row stride (f32): 4-bank shift per row

// prep grid partition (order: sabs | tab | wcat)
#define NS_BLK 4096            // sc_abs+t_emb: 2 rows/block
#define NT_BLK 128             // tab frags: 4/block (512)
#define NW_BLK 64              // wcat frags: 4/block (256)
#define NPREP  (NS_BLK + NT_BLK + NW_BLK)

// workspace layout (full path)
#define TF_BYTES    (KH*256*2)          // 524288 : tab, B-frag order
#define WCAT_BYTES  (512*256*2)         // 262144 : sign-folded w_e, B-frag order
#define SAB_BYTES   (8192*4)            // 32768  : per-row sc_abs, f32
#define WS_FULL     ((size_t)(TF_BYTES + WCAT_BYTES + SAB_BYTES))
// fallback path
#define OLDTAB_BYTES (1000*256*2)
#define WS_OLD       ((size_t)(OLDTAB_BYTES + WCAT_BYTES))

typedef __attribute__((ext_vector_type(8))) short short8v;
typedef __attribute__((ext_vector_type(4))) float float4v;

__device__ __forceinline__ float bfLo(uint32_t u) { return __uint_as_float(u << 16); }
__device__ __forceinline__ float bfHi(uint32_t u) { return __uint_as_float(u & 0xffff0000u); }
__device__ __forceinline__ float bf1(unsigned short u) { return __uint_as_float((uint32_t)u << 16); }

__device__ __forceinline__ uint32_t f2bf_u(float x) {
  uint32_t u = __float_as_uint(x);
  u += 0x7fffu + ((u >> 16) & 1u);   // RNE
  return u >> 16;
}
__device__ __forceinline__ unsigned short f2bf(float x) { return (unsigned short)f2bf_u(x); }

__device__ __forceinline__ short8v cvt8(float4 a, float4 b) {
  short8v r;
  r[0] = (short)f2bf(a.x); r[1] = (short)f2bf(a.y);
  r[2] = (short)f2bf(a.z); r[3] = (short)f2bf(a.w);
  r[4] = (short)f2bf(b.x); r[5] = (short)f2bf(b.y);
  r[6] = (short)f2bf(b.z); r[7] = (short)f2bf(b.w);
  return r;
}

// ---------------------------------------------------------------------------
// Stage 1: per-row sc_abs (t_emb inline) + table builds.
// B-frag swizzle: frag fb, lane l, elem j <-> k=(fb>>4)*32+(l>>4)*8+j, c=(fb&15)*16+(l&15)
__global__ __launch_bounds__(256) void kge_prep3(
    const int* __restrict__ x,
    const float* __restrict__ w_e, const float* __restrict__ e_emb,
    const float* __restrict__ r_emb,
    const float* __restrict__ d_frq, const float* __restrict__ d_phi, const float* __restrict__ d_amp,
    const float* __restrict__ m_frq, const float* __restrict__ m_phi, const float* __restrict__ m_amp,
    unsigned short* __restrict__ tf, unsigned short* __restrict__ wcat,
    float* __restrict__ sabs_buf) {
  __shared__ float st2[2][2][256];         // t_emb f32 (4 KB)
  __shared__ float redl[4];
  const int bid = blockIdx.x;
  const int tid = threadIdx.x;
  const int sub = tid >> 6, l = tid & 63;

  if (bid < NS_BLK) {
    // ---- per-row sc_abs with inline t_emb; 2 rows/block, 128 thr/row ----
    const int rsub = tid >> 7;               // row slot 0/1
    const int row = bid * 2 + rsub;
    const int j = tid & 127;
    const int* xr = x + (size_t)row * XSTR;
    const int eS = xr[0], rid = xr[1], eO = xr[2];
    const float dv = (float)xr[3], mv = (float)xr[4];
    const int j2 = 2 * j;
    #pragma unroll
    for (int ent = 0; ent < 2; ++ent) {
      const int e = ent ? eO : eS;
      float2 fd = *(const float2*)&d_frq[(size_t)e * 256 + j2];
      float2 pd = *(const float2*)&d_phi[(size_t)e * 256 + j2];
      float2 fm = *(const float2*)&m_frq[(size_t)e * 256 + j2];
      float2 pm = *(const float2*)&m_phi[(size_t)e * 256 + j2];
      const int ja = j2 & 127;
      float2 ad = *(const float2*)&d_amp[(size_t)e * 128 + ja];
      float2 am = *(const float2*)&m_amp[(size_t)e * 128 + ja];
      float a0 = fmaf(dv, fd.x, pd.x), a1 = fmaf(dv, fd.y, pd.y);
      float b0 = fmaf(mv, fm.x, pm.x), b1 = fmaf(mv, fm.y, pm.y);
      float t0, t1, u0, u1;
      if (j2 < 128) { t0 = __cosf(a0); t1 = __cosf(a1); u0 = __cosf(b0); u1 = __cosf(b1); }
      else          { t0 = __sinf(a0); t1 = __sinf(a1); u0 = __sinf(b0); u1 = __sinf(b1); }
      st2[rsub][ent][j2]     = fmaf(ad.x, t0, am.x * u0);
      st2[rsub][ent][j2 + 1] = fmaf(ad.y, t1, am.y * u1);
    }
    __syncthreads();
    const float* Es = e_emb + (size_t)eS * 512;
    const float* Eo = e_emb + (size_t)eO * 512;
    const float* Rr = r_emb + (size_t)rid * 384;
    float sabs = 0.f;
    #pragma unroll
    for (int t3 = 0; t3 < 3; ++t3) {
      const int u = t3 * 128 + j;
      float ang = Rr[u] * SCALE_ANG;
      float sr = __sinf(ang), cr = __cosf(ang);
      float res, ims, reo, imo;
      if (t3 < 2) {
        res = Es[u]; ims = Es[256 + u];
        reo = Eo[u]; imo = Eo[256 + u];
      } else {
        res = st2[rsub][0][j]; ims = st2[rsub][0][128 + j];
        reo = st2[rsub][1][j]; imo = st2[rsub][1][128 + j];
      }
      float rsc = res * cr - ims * sr - reo;
      float isc = res * sr + ims * cr - imo;
      sabs += sqrtf(rsc * rsc + isc * isc);
    }
    #pragma unroll
    for (int off = 32; off > 0; off >>= 1) sabs += __shfl_down(sabs, off);
    if (l == 0) redl[sub] = sabs;       // sub = wave id 0..3
    __syncthreads();
    if (j == 0) sabs_buf[row] = redl[2 * rsub] + redl[2 * rsub + 1];
  } else if (bid < NS_BLK + NT_BLK) {
    // ---- tab frags: value(k,c) = k<1000 ? (c<128 ? cos : sin)(k*f_{c&127}) : 0
    const int fragid = (bid - NS_BLK) * 4 + sub;   // kt*16+nt
    const int kt = fragid >> 4, nt = fragid & 15;
    const int c = nt * 16 + (l & 15);
    const float f = exp2f(-(float)(c & 127) * (13.287712379549449f / 128.f));
    __align__(16) unsigned short v[8];
    #pragma unroll
    for (int jj = 0; jj < 8; ++jj) {
      int k = kt * 32 + ((l >> 4) << 3) + jj;
      float val = 0.f;
      if (k < 1000) {
        float s, cv;
        sincosf((float)k * f, &s, &cv);
        val = (c < 128) ? cv : s;
      }
      v[jj] = f2bf(val);
    }
    ((uint4*)tf)[fragid * 64 + l] = *(const uint4*)v;
  } else {
    // ---- Wcat frags: Wcat[k][c] = c<128 ? s(k)*w_e[k][c] : -s(k)*w_e[k^256][c-128]
    const int fragid = (bid - NS_BLK - NT_BLK) * 4 + sub;
    const int kk = fragid >> 4, nt = fragid & 15;
    const int c = nt * 16 + (l & 15);
    __align__(16) unsigned short v[8];
    #pragma unroll
    for (int jj = 0; jj < 8; ++jj) {
      int k = kk * 32 + ((l >> 4) << 3) + jj;
      float s = (k < 256) ? 1.f : -1.f;
      float val = (c < 128) ? s * w_e[k * 128 + c]
                            : -s * w_e[(k ^ 256) * 128 + (c - 128)];
      v[jj] = f2bf(val);
    }
    ((uint4*)wcat)[fragid * 64 + l] = *(const uint4*)v;
  }
}

// ---------------------------------------------------------------------------
// Stage 2: diff-GEMM + sc_rel, histogram built in LDS (no G round-trip).
// Grid: 512 blocks x 256 threads (2 blocks/CU, 2 waves/SIMD). M-tile 16.
// Balanced K-split: wave w does e_emb-diff steps [4w,4w+4) (wcat B) and
// G-steps [8w,8w+8) (tab B, A from LDS hist). LDS hist (16x1028 f32, 65.8KB)
// is aliased by the partials buffer after the post-GEMM barrier.
__global__ __launch_bounds__(256) void kge_fused5(
    const int* __restrict__ x, const float* __restrict__ e_emb,
    const float* __restrict__ w_rp,
    const unsigned short* __restrict__ wcat, const unsigned short* __restrict__ tf,
    const float* __restrict__ sabs_buf, float* __restrict__ out) {
  __shared__ __align__(16) float lds_f[16 * HPAD];   // 65792 B (hist, then partials)
  __shared__ float prel[4][16];
  const int tid = threadIdx.x;
  const int w = tid >> 6, l = tid & 63;
  const int m0 = blockIdx.x * 16;

  // ---- Phase 0: zero hist ----
  #pragma unroll
  for (int i = tid; i < 16 * HPAD / 4; i += 256)
    ((float4*)lds_f)[i] = (float4){0, 0, 0, 0};
  __syncthreads();

  // ---- Phase 1: build 16 signed histograms (16 threads/row) ----
  {
    const int hr = tid >> 4, sub16 = tid & 15;
    const int row = m0 + hr;
    const int* xr = x + (size_t)row * XSTR;
    const int rid = xr[1];
    const int* cp = xr + 6;
    const float* wp = w_rp + (size_t)rid * 200;
    float* hrow = lds_f + hr * HPAD;
    for (int n = sub16; n < 200; n += 16) {
      float wv = wp[n];
      atomicAdd(&hrow[cp[n]], wv);
      atomicAdd(&hrow[cp[200 + n]], -wv);
    }
  }

  // ---- Phase 2a: e_emb-diff K-steps [4w, 4w+4) — no LDS dependency,
  //      overlaps other waves' atomics before the barrier ----
  const int rowA = m0 + (l & 15);
  const int* xrA = x + (size_t)rowA * XSTR;
  const float* Esp = e_emb + (size_t)xrA[0] * 512 + ((l >> 4) << 3);
  const float* Eop = e_emb + (size_t)xrA[2] * 512 + ((l >> 4) << 3);
  const short8v* wq = (const short8v*)wcat;
  const short8v* tq = (const short8v*)tf;

  float4v acc[16];
  #pragma unroll
  for (int i = 0; i < 16; ++i) acc[i] = (float4v){0, 0, 0, 0};

  #pragma unroll
  for (int kt = 4 * w; kt < 4 * w + 4; ++kt) {
    float4 s0 = *(const float4*)(Esp + kt * 32);
    float4 s1 = *(const float4*)(Esp + kt * 32 + 4);
    float4 o0 = *(const float4*)(Eop + kt * 32);
    float4 o1 = *(const float4*)(Eop + kt * 32 + 4);
    float4 d0 = {s0.x - o0.x, s0.y - o0.y, s0.z - o0.z, s0.w - o0.w};
    float4 d1 = {s1.x - o1.x, s1.y - o1.y, s1.z - o1.z, s1.w - o1.w};
    short8v a = cvt8(d0, d1);
    const short8v* bsrc = wq + (size_t)kt * 1024;
    #pragma unroll
    for (int nt = 0; nt < 16; ++nt)
      acc[nt] = __builtin_amdgcn_mfma_f32_16x16x32_bf16(a, bsrc[nt * 64 + l], acc[nt], 0, 0, 0);
  }
  __syncthreads();   // all histograms complete

  // ---- Phase 2b: G K-steps [8w, 8w+8), A from LDS hist ----
  {
    const float* hbase = lds_f + (l & 15) * HPAD + ((l >> 4) << 3);
    #pragma unroll
    for (int g = 8 * w; g < 8 * w + 8; ++g) {
      float4 h0 = *(const float4*)(hbase + g * 32);
      float4 h1 = *(const float4*)(hbase + g * 32 + 4);
      short8v a = cvt8(h0, h1);
      const short8v* bsrc = tq + (size_t)g * 1024;
      #pragma unroll
      for (int nt = 0; nt < 16; ++nt)
        acc[nt] = __builtin_amdgcn_mfma_f32_16x16x32_bf16(a, bsrc[nt * 64 + l], acc[nt], 0, 0, 0);
    }
  }
  __syncthreads();   // hist reads done; lds_f reusable

  // ---- Phase 3: dump partials (alias lds_f as part[4][16][256]) ----
  float* part = lds_f;
  #pragma unroll
  for (int nt = 0; nt < 16; ++nt)
    #pragma unroll
    for (int q = 0; q < 4; ++q)
      part[((w * 16 + nt) * 256) + q * 64 + l] = acc[nt][q];
  __syncthreads();

  // ---- Phase 4: combine; wave w handles re/im pairs (2w,2w+8),(2w+1,2w+9) ----
  {
    float sq[4] = {0.f, 0.f, 0.f, 0.f};
    #pragma unroll
    for (int pp = 0; pp < 2; ++pp) {
      const int p = 2 * w + pp;
      #pragma unroll
      for (int q = 0; q < 4; ++q) {
        const int idx = q * 64 + l;
        float dre = part[(0 * 16 + p) * 256 + idx] + part[(1 * 16 + p) * 256 + idx]
                  + part[(2 * 16 + p) * 256 + idx] + part[(3 * 16 + p) * 256 + idx];
        float dim = part[(0 * 16 + p + 8) * 256 + idx] + part[(1 * 16 + p + 8) * 256 + idx]
                  + part[(2 * 16 + p + 8) * 256 + idx] + part[(3 * 16 + p + 8) * 256 + idx];
        sq[q] += sqrtf(dre * dre + dim * dim);
      }
    }
    #pragma unroll
    for (int q = 0; q < 4; ++q) {
      float s = sq[q];
      s += __shfl_xor(s, 1); s += __shfl_xor(s, 2);
      s += __shfl_xor(s, 4); s += __shfl_xor(s, 8);
      if ((l & 15) == 0) prel[w][(l >> 4) * 4 + q] = s;
    }
  }
  __syncthreads();
  if (tid < 16) {
    const int r = tid;
    float srel = prel[0][r] + prel[1][r] + prel[2][r] + prel[3][r];
    out[m0 + r] = GAMMA_C - (sabs_buf[m0 + r] + srel);
  }
}

// ===========================================================================
// Fallback path (workspace >= 774 KB but < WS_FULL): round-3 kernel.
#define NTH    512
#define RPB    8
#define ERB    (2*RPB)
#define APAD   520

__global__ void kge_table_old(unsigned short* __restrict__ tab) {
  int t = blockIdx.x;
  int j = threadIdx.x;
  double f = pow(10000.0, -(double)j / 128.0);
  double ang = (double)t * f;
  int q = j >> 1, lo = j & 1;
  tab[t * 256 + 4 * q + lo]     = f2bf((float)cos(ang));
  tab[t * 256 + 4 * q + 2 + lo] = f2bf((float)sin(ang));
}

__global__ void kge_wcat_old(const float* __restrict__ w_e, unsigned short* __restrict__ wcat) {
  int bid = blockIdx.x;
  int kk = bid >> 4, nt = bid & 15;
  int l = threadIdx.x;
  __align__(16) unsigned short v[8];
  int c = nt * 16 + (l & 15);
  #pragma unroll
  for (int j = 0; j < 8; ++j) {
    int k = kk * 32 + ((l >> 4) << 3) + j;
    float s = (k < 256) ? 1.f : -1.f;
    float val = (c < 128) ? s * w_e[k * 128 + c]
                          : -s * w_e[(k ^ 256) * 128 + (c - 128)];
    v[j] = f2bf(val);
  }
  ((uint4*)wcat)[bid * 64 + l] = *(const uint4*)v;
}

__global__ __launch_bounds__(NTH, 4) void kge_main3(
    const int* __restrict__ x,
    const float* __restrict__ e_emb, const float* __restrict__ r_emb,
    const float* __restrict__ d_frq, const float* __restrict__ d_phi, const float* __restrict__ d_amp,
    const float* __restrict__ m_frq, const float* __restrict__ m_phi, const float* __restrict__ m_amp,
    const float* __restrict__ w_rp,
    const unsigned short* __restrict__ tab, const unsigned short* __restrict__ wcat,
    float* __restrict__ out) {
  __shared__ __align__(16) unsigned short A[ERB][APAD];
  __shared__ __align__(16) unsigned short stb[ERB][256];
  __shared__ __align__(16) float p[ERB][256];
  __shared__ int meta[RPB][6];

  const int tid = threadIdx.x;
  const int base_row = blockIdx.x * RPB;
  const int w = tid >> 6, l = tid & 63;

  if (tid < RPB * 6) {
    int r = tid / 6, f = tid % 6;
    meta[r][f] = x[(size_t)(base_row + r) * XSTR + f];
  }
  __syncthreads();

  for (int i = tid; i < ERB * 128; i += NTH) {
    int er = i >> 7, k4 = i & 127;
    int e = (er & 1) ? meta[er >> 1][2] : meta[er >> 1][0];
    float4 v = ((const float4*)e_emb)[(size_t)e * 128 + k4];
    uint2 pk;
    pk.x = f2bf_u(v.x) | (f2bf_u(v.y) << 16);
    pk.y = f2bf_u(v.z) | (f2bf_u(v.w) << 16);
    *(uint2*)&A[er][k4 * 4] = pk;
  }
  for (int it = tid; it < ERB * 256; it += NTH) {
    int j = it & 255, er = it >> 8, r = er >> 1;
    int e = (er & 1) ? meta[r][2] : meta[r][0];
    float dv = (float)meta[r][3], mv = (float)meta[r][4];
    size_t b256 = (size_t)e * 256 + j, b128 = (size_t)e * 128 + (j & 127);
    float argd = fmaf(dv, d_frq[b256], d_phi[b256]);
    float argm = fmaf(mv, m_frq[b256], m_phi[b256]);
    float vd = (j < 128) ? d_amp[b128] * __cosf(argd) : d_amp[b128] * __sinf(argd);
    float vm = (j < 128) ? m_amp[b128] * __cosf(argm) : m_amp[b128] * __sinf(argm);
    stb[er][j] = f2bf(vd + vm);
  }

  float s0 = 0, s1 = 0, s2 = 0, s3 = 0, o0 = 0, o1 = 0, o2 = 0, o3 = 0;
  {
    const int wu  = __builtin_amdgcn_readfirstlane(w);
    const int rid = __builtin_amdgcn_readfirstlane(meta[wu][1]);
    const int*   cp = x + (size_t)(base_row + wu) * XSTR + 6;
    const float* wp = w_rp + (size_t)rid * 200;
    const uint2* tl = ((const uint2*)tab) + l;
    #pragma unroll 2
    for (int n = 0; n < 200; ++n) {
      float wv = wp[n];
      int cS = cp[n];
      int cO = cp[200 + n];
      uint2 qs = tl[(size_t)cS * 64];
      uint2 qo = tl[(size_t)cO * 64];
      s0 = fmaf(wv, bfLo(qs.x), s0); s1 = fmaf(wv, bfHi(qs.x), s1);
      s2 = fmaf(wv, bfLo(qs.y), s2); s3 = fmaf(wv, bfHi(qs.y), s3);
      o0 = fmaf(wv, bfLo(qo.x), o0); o1 = fmaf(wv, bfHi(qo.x), o1);
      o2 = fmaf(wv, bfLo(qo.y), o2); o3 = fmaf(wv, bfHi(qo.y), o3);
    }
  }
  __syncthreads();

  {
    float4v acc0 = {0, 0, 0, 0}, acc1 = {0, 0, 0, 0};
    const int nt0 = 2 * w, nt1 = 2 * w + 1;
    const short8v* bp = (const short8v*)wcat;
    const unsigned short* arow = &A[l & 15][(l >> 4) << 3];
    #pragma unroll 8
    for (int kk = 0; kk < 16; ++kk) {
      short8v a  = *(const short8v*)(arow + kk * 32);
      short8v b0 = bp[(kk * 16 + nt0) * 64 + l];
      short8v b1 = bp[(kk * 16 + nt1) * 64 + l];
      acc0 = __builtin_amdgcn_mfma_f32_16x16x32_bf16(a, b0, acc0, 0, 0, 0);
      acc1 = __builtin_amdgcn_mfma_f32_16x16x32_bf16(a, b1, acc1, 0, 0, 0);
    }
    int col = l & 15, rbase = (l >> 4) * 4;
    #pragma unroll
    for (int q = 0; q < 4; ++q) {
      p[rbase + q][nt0 * 16 + col] = acc0[q];
      p[rbase + q][nt1 * 16 + col] = acc1[q];
    }
  }
  __syncthreads();

  {
    int es = 2 * w, eo = 2 * w + 1;
    p[es][2 * l] += s0; p[es][2 * l + 1] += s1;
    p[es][128 + 2 * l] += s2; p[es][129 + 2 * l] += s3;
    p[eo][2 * l] += o0; p[eo][2 * l + 1] += o1;
    p[eo][128 + 2 * l] += o2; p[eo][129 + 2 * l] += o3;
  }
  __syncthreads();

  {
    int r = w;
    int rid = meta[r][1];
    float sabs = 0.f;
    #pragma unroll
    for (int u0 = 0; u0 < 384; u0 += 64) {
      int u = u0 + l;
      float ang = r_emb[(size_t)rid * 384 + u] * SCALE_ANG;
      float sr = __sinf(ang), cr = __cosf(ang);
      float res, ims, reo, imo;
      if (u < 256) {
        res = bf1(A[2 * r][u]);       ims = bf1(A[2 * r][256 + u]);
        reo = bf1(A[2 * r + 1][u]);   imo = bf1(A[2 * r + 1][256 + u]);
      } else {
        int uu = u - 256;
        res = bf1(stb[2 * r][uu]);     ims = bf1(stb[2 * r][128 + uu]);
        reo = bf1(stb[2 * r + 1][uu]); imo = bf1(stb[2 * r + 1][128 + uu]);
      }
      float rsc = res * cr - ims * sr - reo;
      float isc = res * sr + ims * cr - imo;
      sabs += sqrtf(rsc * rsc + isc * isc);
    }
    float srel = 0.f;
    #pragma unroll
    for (int u0 = 0; u0 < 128; u0 += 64) {
      int u = u0 + l;
      float dre = p[2 * r][u] - p[2 * r + 1][u];
      float dim = p[2 * r][128 + u] - p[2 * r + 1][128 + u];
      srel += sqrtf(dre * dre + dim * dim);
    }
    float tot = sabs + srel;
    #pragma unroll
    for (int off = 32; off > 0; off >>= 1) tot += __shfl_down(tot, off);
    if (l == 0) out[base_row + r] = GAMMA_C - tot;
  }
}

// ===========================================================================
extern "C" void kernel_launch(void* const* d_in, const int* in_sizes, int n_in,
                              void* d_out, int out_size, void* d_ws, size_t ws_size,
                              hipStream_t stream) {
  (void)in_sizes; (void)n_in; (void)out_size;
  const int*   x     = (const int*)d_in[0];
  const float* e_emb = (const float*)d_in[1];
  const float* r_emb = (const float*)d_in[2];
  const float* d_frq = (const float*)d_in[3];
  const float* d_phi = (const float*)d_in[4];
  const float* d_amp = (const float*)d_in[5];
  const float* m_frq = (const float*)d_in[6];
  const float* m_phi = (const float*)d_in[7];
  const float* m_amp = (const float*)d_in[8];
  const float* w_e   = (const float*)d_in[9];
  const float* w_rp  = (const float*)d_in[10];
  float* out = (float*)d_out;

  if (ws_size >= WS_FULL) {
    char* base = (char*)d_ws;
    unsigned short* tf    = (unsigned short*)base;
    unsigned short* wcat  = (unsigned short*)(base + TF_BYTES);
    float*          sabsb = (float*)(base + TF_BYTES + WCAT_BYTES);
    kge_prep3<<<dim3(NPREP), dim3(256), 0, stream>>>(
        x, w_e, e_emb, r_emb, d_frq, d_phi, d_amp, m_frq, m_phi, m_amp,
        tf, wcat, sabsb);
    kge_fused5<<<dim3(B_ROWS / 16), dim3(256), 0, stream>>>(
        x, e_emb, w_rp, wcat, tf, sabsb, out);
  } else if (ws_size >= WS_OLD) {
    unsigned short* tab  = (unsigned short*)d_ws;
    unsigned short* wcat = (unsigned short*)((char*)d_ws + OLDTAB_BYTES);
    kge_table_old<<<dim3(1000), dim3(128), 0, stream>>>(tab);
    kge_wcat_old<<<dim3(256), dim3(64), 0, stream>>>(w_e, wcat);
    kge_main3<<<dim3(B_ROWS / RPB), dim3(NTH), 0, stream>>>(
        x, e_emb, r_emb, d_frq, d_phi, d_amp, m_frq, m_phi, m_amp, w_rp,
        tab, wcat, out);
  }
}